// Round 1
// baseline (225.673 us; speedup 1.0000x reference)
//
#include <hip/hip_runtime.h>

#define EMD 128   // embedding dim
// K (number of score channels) is fixed at 2 by the problem (psi is (2,1)).

__device__ __forceinline__ float softplus_f(float x) {
    // jax.nn.softplus(x) = logaddexp(x, 0) = max(x,0) + log1p(exp(-|x|))
    return fmaxf(x, 0.0f) + log1pf(expf(-fabsf(x)));
}

__device__ __forceinline__ float wred(float v) {
    #pragma unroll
    for (int m = 32; m >= 1; m >>= 1) v += __shfl_xor(v, m, 64);
    return v;
}

__global__ __launch_bounds__(256) void dynemb_kernel(
    const int*   __restrict__ input,    // (B,5)
    const int*   __restrict__ neg_idx,  // (B,N,2)
    const float* __restrict__ emb,      // (NSIZE,128)
    const float* __restrict__ W0,       // (256,)
    const float* __restrict__ b0v,      // (1,)
    const float* __restrict__ W1,       // (256,)
    const float* __restrict__ b1v,      // (1,)
    const float* __restrict__ psi,      // (2,)
    float*       __restrict__ out,      // [0..B) intensity, [B..2B) surv
    int B, int N, int K)
{
    const int b    = blockIdx.x;
    const int tid  = threadIdx.x;
    const int wave = tid >> 6;
    const int lane = tid & 63;

    // per-lane weight fragments: lane holds elements (2*lane, 2*lane+1)
    const float2 wa0 = *reinterpret_cast<const float2*>(&W0[2 * lane]);        // Wa[0]
    const float2 wa1 = *reinterpret_cast<const float2*>(&W1[2 * lane]);        // Wa[1]
    const float2 wb0 = *reinterpret_cast<const float2*>(&W0[EMD + 2 * lane]);  // Wb[0]
    const float2 wb1 = *reinterpret_cast<const float2*>(&W1[EMD + 2 * lane]);  // Wb[1]

    const float bb0 = b0v[0], bb1 = b1v[0];
    const float p0  = psi[0], p1  = psi[1];

    const int v1 = input[b * 5 + 0];
    const int v2 = input[b * 5 + 1];

    const float2* emb2 = reinterpret_cast<const float2*>(emb);

    // e1 = emb[v1], e2 = emb[v2]; every wave computes the 4 base dots itself
    // (redundant loads hit L1/L2 — avoids an extra LDS roundtrip)
    const float2 x1 = emb2[(size_t)v1 * (EMD / 2) + lane];
    const float2 x2 = emb2[(size_t)v2 * (EMD / 2) + lane];

    const float a0 = wred(x1.x * wa0.x + x1.y * wa0.y);  // e1 . Wa0
    const float a1 = wred(x1.x * wa1.x + x1.y * wa1.y);  // e1 . Wa1
    const float c0 = wred(x2.x * wb0.x + x2.y * wb0.y);  // e2 . Wb0
    const float c1 = wred(x2.x * wb1.x + x2.y * wb1.y);  // e2 . Wb1

    float acc = 0.0f;
    for (int n = wave; n < N; n += 4) {
        const int i1 = neg_idx[((size_t)b * N + n) * 2 + 0];
        const int i2 = neg_idx[((size_t)b * N + n) * 2 + 1];
        const float2 y1 = emb2[(size_t)i1 * (EMD / 2) + lane];  // eo1 row
        const float2 y2 = emb2[(size_t)i2 * (EMD / 2) + lane];  // eo2 row

        const float d0 = wred(y2.x * wb0.x + y2.y * wb0.y);  // eo2 . Wb0
        const float d1 = wred(y2.x * wb1.x + y2.y * wb1.y);  // eo2 . Wb1
        const float g0 = wred(y1.x * wa0.x + y1.y * wa0.y);  // eo1 . Wa0
        const float g1 = wred(y1.x * wa1.x + y1.y * wa1.y);  // eo1 . Wa1

        // s1[n,k] = a_k + (eo2.Wb_k) + bb_k ;  s2[n,k] = (eo1.Wa_k) + c_k + bb_k
        acc += p0 * softplus_f((a0 + d0 + bb0) / p0);
        acc += p1 * softplus_f((a1 + d1 + bb1) / p1);
        acc += p0 * softplus_f((g0 + c0 + bb0) / p0);
        acc += p1 * softplus_f((g1 + c1 + bb1) / p1);
    }

    __shared__ float s_acc[4];
    if (lane == 0) s_acc[wave] = acc;
    __syncthreads();

    if (tid == 0) {
        const float surv = (s_acc[0] + s_acc[1] + s_acc[2] + s_acc[3]) / (float)N;
        out[B + b] = surv;

        const int   k  = input[b * 5 + 4] % K;   // K = 2
        const float pk = (k != 0) ? p1 : p0;
        const float sk = (k != 0) ? (a1 + c1 + bb1) : (a0 + c0 + bb0);
        out[b] = pk * softplus_f(sk / pk);
    }
}

extern "C" void kernel_launch(void* const* d_in, const int* in_sizes, int n_in,
                              void* d_out, int out_size, void* d_ws, size_t ws_size,
                              hipStream_t stream)
{
    const int*   input = (const int*)d_in[0];
    const int*   neg   = (const int*)d_in[1];
    // d_in[2] is N (device scalar) — derive from sizes instead (host-visible)
    const float* emb   = (const float*)d_in[3];
    const float* W0    = (const float*)d_in[4];
    const float* b0    = (const float*)d_in[5];
    const float* W1    = (const float*)d_in[6];
    const float* b1    = (const float*)d_in[7];
    const float* psi   = (const float*)d_in[8];

    const int B = in_sizes[0] / 5;
    const int N = in_sizes[1] / (2 * B);
    const int K = in_sizes[8];  // psi is (K,1) -> K = 2

    float* out = (float*)d_out;

    dynemb_kernel<<<B, 256, 0, stream>>>(input, neg, emb, W0, b0, W1, b1, psi,
                                         out, B, N, K);
}

// Round 2
// 61.996 us; speedup vs baseline: 3.6401x; 3.6401x over previous
//
#include <hip/hip_runtime.h>

#define EMD 128   // embedding dim (fixed by problem)
// K (score channels) is fixed at 2 (psi is (2,1)); the lane-parity scheme
// below hardcodes K=2.

__global__ __launch_bounds__(256) void dynemb_kernel(
    const int*   __restrict__ input,    // (B,5)
    const int*   __restrict__ neg_idx,  // (B,N,2)
    const float* __restrict__ emb,      // (NSIZE,128)
    const float* __restrict__ W0,       // (256,)
    const float* __restrict__ b0v,      // (1,)
    const float* __restrict__ W1,       // (256,)
    const float* __restrict__ b1v,      // (1,)
    const float* __restrict__ psi,      // (2,)
    float*       __restrict__ out,      // [0..B) intensity, [B..2B) surv
    int B, int N)
{
    const int b    = blockIdx.x;
    const int tid  = threadIdx.x;
    const int wave = tid >> 6;
    const int lane = tid & 63;
    const int h    = lane >> 5;        // half: 0 -> row1 (Wa), 1 -> row2 (Wb)
    const int j    = lane & 31;        // position within half (float4 index)
    const int par  = lane & 1;         // parity: 0 -> channel k=0, 1 -> k=1

    const float4* emb4 = reinterpret_cast<const float4*>(emb);
    const float4* W0_4 = reinterpret_cast<const float4*>(W0);
    const float4* W1_4 = reinterpret_cast<const float4*>(W1);

    // per-lane weight fragments: half h, chunk j
    //   h=0: wA=Wa0 (W0[:128]),  wB=Wa1 (W1[:128])
    //   h=1: wA=Wb0 (W0[128:]),  wB=Wb1 (W1[128:])
    const float4 wA = W0_4[h * 32 + j];
    const float4 wB = W1_4[h * 32 + j];

    const float bb  = par ? b1v[0]  : b0v[0];
    const float pp  = par ? psi[1]  : psi[0];
    const float ipp = 1.0f / pp;

    const int v1 = input[b * 5 + 0];
    const int v2 = input[b * 5 + 1];

    // ---- base dots: half 0 computes e1.Wa_k, half 1 computes e2.Wb_k ----
    {
        const float4 y = emb4[(size_t)(h ? v2 : v1) * 32 + j];
        const float u0 = y.x * wA.x + y.y * wA.y + y.z * wA.z + y.w * wA.w;
        const float u1 = y.x * wB.x + y.y * wB.y + y.z * wB.z + y.w * wB.w;
        float z = (par ? u1 : u0) + __shfl_xor(par ? u0 : u1, 1, 64);
        z += __shfl_xor(z, 2, 64);
        z += __shfl_xor(z, 4, 64);
        z += __shfl_xor(z, 8, 64);
        z += __shfl_xor(z, 16, 64);
        // lane (h,par) holds: h=0 -> a_par (e1.Wa_par); h=1 -> c_par (e2.Wb_par)
        const float cross = __shfl_xor(z, 32, 64);  // partner half, same parity
        const float base  = cross + bb;             // (loop adds own-half dot)

        // intensity (wave 0 writes it)
        const float sboth = z + base;               // = a_par + c_par + bb_par
        const float x  = sboth * ipp;
        const float iv = pp * (fmaxf(x, 0.0f) + log1pf(__expf(-fabsf(x))));
        if (wave == 0) {
            const int k = input[b * 5 + 4] & 1;     // K = 2
            const float ival = __shfl(iv, k, 64);
            if (tid == 0) out[b] = ival;
        }

        // ---- negative-sample loop: 4 dots per n in 5 shuffles ----
        const int npw   = N >> 2;                   // n's per wave (16)
        const int nch   = npw >> 2;                 // chunks of 4 (4)
        const int2* nip = reinterpret_cast<const int2*>(
                              &neg_idx[((size_t)b * N + wave * npw) * 2]);

        float acc = 0.0f;

        int2   idx[4];
        float4 rows[4];
        #pragma unroll
        for (int t = 0; t < 4; ++t) idx[t] = nip[t];
        #pragma unroll
        for (int t = 0; t < 4; ++t)
            rows[t] = emb4[(size_t)(h ? idx[t].y : idx[t].x) * 32 + j];

        for (int c = 0; c < nch; ++c) {
            int2   idxn[4];
            float4 rown[4];
            const bool more = (c + 1 < nch);
            if (more) {
                #pragma unroll
                for (int t = 0; t < 4; ++t) idxn[t] = nip[(c + 1) * 4 + t];
                #pragma unroll
                for (int t = 0; t < 4; ++t)
                    rown[t] = emb4[(size_t)(h ? idxn[t].y : idxn[t].x) * 32 + j];
            }
            #pragma unroll
            for (int t = 0; t < 4; ++t) {
                const float4 y = rows[t];
                const float u0 = y.x * wA.x + y.y * wA.y + y.z * wA.z + y.w * wA.w;
                const float u1 = y.x * wB.x + y.y * wB.y + y.z * wB.z + y.w * wB.w;
                float z = (par ? u1 : u0) + __shfl_xor(par ? u0 : u1, 1, 64);
                z += __shfl_xor(z, 2, 64);
                z += __shfl_xor(z, 4, 64);
                z += __shfl_xor(z, 8, 64);
                z += __shfl_xor(z, 16, 64);
                // z: (h=0) eo1.Wa_par ; (h=1) eo2.Wb_par   (x16 replicated)
                const float xx = (z + base) * ipp;
                acc += fmaxf(xx, 0.0f) + log1pf(__expf(-fabsf(xx)));
            }
            if (more) {
                #pragma unroll
                for (int t = 0; t < 4; ++t) { idx[t] = idxn[t]; rows[t] = rown[t]; }
            }
        }
        acc *= pp;   // per-lane psi multiplier hoisted out of the loop

        // block reduction: every term is replicated 16x within its half
        #pragma unroll
        for (int m = 32; m >= 1; m >>= 1) acc += __shfl_xor(acc, m, 64);

        __shared__ float s_acc[4];
        if (lane == 0) s_acc[wave] = acc;
        __syncthreads();
        if (tid == 0) {
            const float total = s_acc[0] + s_acc[1] + s_acc[2] + s_acc[3];
            out[B + b] = total * (1.0f / (16.0f * (float)N));
        }
    }
}

extern "C" void kernel_launch(void* const* d_in, const int* in_sizes, int n_in,
                              void* d_out, int out_size, void* d_ws, size_t ws_size,
                              hipStream_t stream)
{
    const int*   input = (const int*)d_in[0];
    const int*   neg   = (const int*)d_in[1];
    const float* emb   = (const float*)d_in[3];
    const float* W0    = (const float*)d_in[4];
    const float* b0    = (const float*)d_in[5];
    const float* W1    = (const float*)d_in[6];
    const float* b1    = (const float*)d_in[7];
    const float* psi   = (const float*)d_in[8];

    const int B = in_sizes[0] / 5;
    const int N = in_sizes[1] / (2 * B);

    float* out = (float*)d_out;

    dynemb_kernel<<<B, 256, 0, stream>>>(input, neg, emb, W0, b0, W1, b1, psi,
                                         out, B, N);
}

// Round 3
// 47.915 us; speedup vs baseline: 4.7099x; 1.2939x over previous
//
#include <hip/hip_runtime.h>

#define EMD 128   // embedding dim (fixed by problem)
// K (score channels) fixed at 2 (psi is (2,1)); lane-parity scheme hardcodes K=2.

__global__ __launch_bounds__(256, 8) void dynemb_kernel(
    const int*   __restrict__ input,    // (B,5)
    const int*   __restrict__ neg_idx,  // (B,N,2)
    const float* __restrict__ emb,      // (NSIZE,128)
    const float* __restrict__ W0,       // (256,)
    const float* __restrict__ b0v,      // (1,)
    const float* __restrict__ W1,       // (256,)
    const float* __restrict__ b1v,      // (1,)
    const float* __restrict__ psi,      // (2,)
    float*       __restrict__ out,      // [0..B) intensity, [B..2B) surv
    int B, int N)
{
    const int b    = blockIdx.x;
    const int tid  = threadIdx.x;
    const int wave = tid >> 6;
    const int lane = tid & 63;
    const int h    = lane >> 5;        // half: 0 -> row1 side (Wa), 1 -> row2 side (Wb)
    const int j    = lane & 31;        // float4 chunk within row
    const int par  = lane & 1;         // parity: channel k

    const float4* emb4 = reinterpret_cast<const float4*>(emb);
    const float4* W0_4 = reinterpret_cast<const float4*>(W0);
    const float4* W1_4 = reinterpret_cast<const float4*>(W1);

    // per-lane weight fragments (h=0: Wa0/Wa1 ; h=1: Wb0/Wb1)
    const float4 wA = W0_4[h * 32 + j];
    const float4 wB = W1_4[h * 32 + j];

    const float bb  = par ? b1v[0] : b0v[0];
    const float pp  = par ? psi[1] : psi[0];
    const float ipp = 1.0f / pp;

    const int v1 = input[b * 5 + 0];
    const int v2 = input[b * 5 + 1];

    // ---- base dots: half 0 -> e1.Wa_k ; half 1 -> e2.Wb_k ----
    float base;
    {
        const float4 y = emb4[(size_t)(h ? v2 : v1) * 32 + j];
        const float u0 = y.x * wA.x + y.y * wA.y + y.z * wA.z + y.w * wA.w;
        const float u1 = y.x * wB.x + y.y * wB.y + y.z * wB.z + y.w * wB.w;
        float z = (par ? u1 : u0) + __shfl_xor(par ? u0 : u1, 1, 64);
        z += __shfl_xor(z, 2, 64);
        z += __shfl_xor(z, 4, 64);
        z += __shfl_xor(z, 8, 64);
        z += __shfl_xor(z, 16, 64);
        const float cross = __shfl_xor(z, 32, 64);  // partner-half dot, same parity
        base = cross + bb;

        // intensity: s_k = a_k + c_k + bb_k = z + base
        const float x  = (z + base) * ipp;
        const float t1 = __expf(-fabsf(x));
        const float iv = pp * (fmaxf(x, 0.0f) + __logf(1.0f + t1));
        if (wave == 0) {
            const int k = input[b * 5 + 4] & 1;     // K = 2
            const float ival = __shfl(iv, k, 64);
            if (tid == 0) out[b] = ival;
        }
    }

    // ---- negative loop: 16 n per wave, 8-deep register ring ----
    // One coalesced dword/lane grabs all 16 index pairs for this wave.
    const int* nip = neg_idx + ((size_t)b * N + wave * 16) * 2;
    const int idxv = nip[lane & 31];   // lane l holds int #l of the 32-int strip

    float4 rows[8];
    #pragma unroll
    for (int t = 0; t < 8; ++t) {
        const int i = __shfl(idxv, 2 * t + h, 64);  // h=0 -> .x ; h=1 -> .y
        rows[t] = emb4[(size_t)i * 32 + j];
    }

    float acc = 0.0f;
    #pragma unroll
    for (int t = 0; t < 16; ++t) {
        const float4 y = rows[t & 7];
        if (t + 8 < 16) {
            const int i = __shfl(idxv, 2 * (t + 8) + h, 64);
            rows[t & 7] = emb4[(size_t)i * 32 + j];
        }
        const float u0 = y.x * wA.x + y.y * wA.y + y.z * wA.z + y.w * wA.w;
        const float u1 = y.x * wB.x + y.y * wB.y + y.z * wB.z + y.w * wB.w;
        float z = (par ? u1 : u0) + __shfl_xor(par ? u0 : u1, 1, 64);
        z += __shfl_xor(z, 2, 64);
        z += __shfl_xor(z, 4, 64);
        z += __shfl_xor(z, 8, 64);
        z += __shfl_xor(z, 16, 64);
        // z: (h=0) eo1.Wa_par ; (h=1) eo2.Wb_par   (16x replicated per half)
        const float xx = (z + base) * ipp;
        const float tt = __expf(-fabsf(xx));
        acc += fmaxf(xx, 0.0f) + __logf(1.0f + tt);
    }
    acc *= pp;   // psi multiplier hoisted

    // block reduction (each softplus term replicated 16x)
    #pragma unroll
    for (int m = 32; m >= 1; m >>= 1) acc += __shfl_xor(acc, m, 64);

    __shared__ float s_acc[4];
    if (lane == 0) s_acc[wave] = acc;
    __syncthreads();
    if (tid == 0) {
        const float total = s_acc[0] + s_acc[1] + s_acc[2] + s_acc[3];
        out[B + b] = total * (1.0f / (16.0f * (float)N));
    }
}

extern "C" void kernel_launch(void* const* d_in, const int* in_sizes, int n_in,
                              void* d_out, int out_size, void* d_ws, size_t ws_size,
                              hipStream_t stream)
{
    const int*   input = (const int*)d_in[0];
    const int*   neg   = (const int*)d_in[1];
    const float* emb   = (const float*)d_in[3];
    const float* W0    = (const float*)d_in[4];
    const float* b0    = (const float*)d_in[5];
    const float* W1    = (const float*)d_in[6];
    const float* b1    = (const float*)d_in[7];
    const float* psi   = (const float*)d_in[8];

    const int B = in_sizes[0] / 5;
    const int N = in_sizes[1] / (2 * B);

    float* out = (float*)d_out;

    dynemb_kernel<<<B, 256, 0, stream>>>(input, neg, emb, W0, b0, W1, b1, psi,
                                         out, B, N);
}

// Round 4
// 44.665 us; speedup vs baseline: 5.0525x; 1.0727x over previous
//
#include <hip/hip_runtime.h>

#define EMD 128   // embedding dim (fixed by problem)
// K (score channels) fixed at 2 (psi is (2,1)); lane-parity scheme hardcodes K=2.
// N (negatives) fixed at 64 by the problem; 8 waves x 8 negatives per block.

__global__ __launch_bounds__(512, 4) void dynemb_kernel(
    const int*   __restrict__ input,    // (B,5)
    const int*   __restrict__ neg_idx,  // (B,N,2)
    const float* __restrict__ emb,      // (NSIZE,128)
    const float* __restrict__ W0,       // (256,)
    const float* __restrict__ b0v,      // (1,)
    const float* __restrict__ W1,       // (256,)
    const float* __restrict__ b1v,      // (1,)
    const float* __restrict__ psi,      // (2,)
    float*       __restrict__ out,      // [0..B) intensity, [B..2B) surv
    int B, int N)
{
    const int b    = blockIdx.x;
    const int tid  = threadIdx.x;
    const int wave = tid >> 6;
    const int lane = tid & 63;
    const int h    = lane >> 5;        // half: 0 -> row1 side (Wa), 1 -> row2 side (Wb)
    const int j    = lane & 31;        // float4 chunk within row
    const int par  = lane & 1;         // parity: channel k

    const float4* emb4 = reinterpret_cast<const float4*>(emb);
    const float4* W0_4 = reinterpret_cast<const float4*>(W0);
    const float4* W1_4 = reinterpret_cast<const float4*>(W1);

    // per-lane weight fragments (h=0: Wa0/Wa1 ; h=1: Wb0/Wb1)
    const float4 wA = W0_4[h * 32 + j];
    const float4 wB = W1_4[h * 32 + j];

    const float bb  = par ? b1v[0] : b0v[0];
    const float pp  = par ? psi[1] : psi[0];
    const float ipp = 1.0f / pp;

    const int v1 = input[b * 5 + 0];
    const int v2 = input[b * 5 + 1];

    // ---- negative indices for this wave: 8 n -> 16 ints, one dword/lane ----
    const int* nip  = neg_idx + ((size_t)b * N + wave * 8) * 2;
    const int  idxv = nip[lane & 15];   // lanes 0..15 hold ints 0..15 (rest broadcast)

    // ---- full upfront prefetch: 8 rows in flight per wave ----
    float4 rows[8];
    #pragma unroll
    for (int t = 0; t < 8; ++t) {
        const int i = __shfl(idxv, 2 * t + h, 64);  // h=0 -> eo1 idx ; h=1 -> eo2 idx
        rows[t] = emb4[(size_t)i * 32 + j];
    }

    // ---- base dots: half 0 -> e1.Wa_k ; half 1 -> e2.Wb_k ----
    float base;
    {
        const float4 y = emb4[(size_t)(h ? v2 : v1) * 32 + j];
        const float u0 = y.x * wA.x + y.y * wA.y + y.z * wA.z + y.w * wA.w;
        const float u1 = y.x * wB.x + y.y * wB.y + y.z * wB.z + y.w * wB.w;
        float z = (par ? u1 : u0) + __shfl_xor(par ? u0 : u1, 1, 64);
        z += __shfl_xor(z, 2, 64);
        z += __shfl_xor(z, 4, 64);
        z += __shfl_xor(z, 8, 64);
        z += __shfl_xor(z, 16, 64);
        const float cross = __shfl_xor(z, 32, 64);  // partner-half dot, same parity
        base = cross + bb;

        // intensity: s_k = a_k + c_k + bb_k = z + base
        const float x  = (z + base) * ipp;
        const float t1 = __expf(-fabsf(x));
        const float iv = pp * (fmaxf(x, 0.0f) + __logf(1.0f + t1));
        if (wave == 0) {
            const int k = input[b * 5 + 4] & 1;     // K = 2
            const float ival = __shfl(iv, k, 64);
            if (tid == 0) out[b] = ival;
        }
    }

    // ---- consume the 8 prefetched rows ----
    float acc = 0.0f;
    #pragma unroll
    for (int t = 0; t < 8; ++t) {
        const float4 y = rows[t];
        const float u0 = y.x * wA.x + y.y * wA.y + y.z * wA.z + y.w * wA.w;
        const float u1 = y.x * wB.x + y.y * wB.y + y.z * wB.z + y.w * wB.w;
        float z = (par ? u1 : u0) + __shfl_xor(par ? u0 : u1, 1, 64);
        z += __shfl_xor(z, 2, 64);
        z += __shfl_xor(z, 4, 64);
        z += __shfl_xor(z, 8, 64);
        z += __shfl_xor(z, 16, 64);
        // z: (h=0) eo1.Wa_par ; (h=1) eo2.Wb_par   (16x replicated per half)
        const float xx = (z + base) * ipp;
        const float tt = __expf(-fabsf(xx));
        acc += fmaxf(xx, 0.0f) + __logf(1.0f + tt);
    }
    acc *= pp;   // psi multiplier hoisted

    // wave reduction (each softplus term replicated 16x within its half)
    #pragma unroll
    for (int m = 32; m >= 1; m >>= 1) acc += __shfl_xor(acc, m, 64);

    __shared__ float s_acc[8];
    if (lane == 0) s_acc[wave] = acc;
    __syncthreads();
    if (tid == 0) {
        float total = 0.0f;
        #pragma unroll
        for (int w = 0; w < 8; ++w) total += s_acc[w];
        out[B + b] = total * (1.0f / (16.0f * (float)N));
    }
}

extern "C" void kernel_launch(void* const* d_in, const int* in_sizes, int n_in,
                              void* d_out, int out_size, void* d_ws, size_t ws_size,
                              hipStream_t stream)
{
    const int*   input = (const int*)d_in[0];
    const int*   neg   = (const int*)d_in[1];
    const float* emb   = (const float*)d_in[3];
    const float* W0    = (const float*)d_in[4];
    const float* b0    = (const float*)d_in[5];
    const float* W1    = (const float*)d_in[6];
    const float* b1    = (const float*)d_in[7];
    const float* psi   = (const float*)d_in[8];

    const int B = in_sizes[0] / 5;
    const int N = in_sizes[1] / (2 * B);   // 64

    float* out = (float*)d_out;

    dynemb_kernel<<<B, 512, 0, stream>>>(input, neg, emb, W0, b0, W1, b1, psi,
                                         out, B, N);
}